// Round 11
// baseline (559.361 us; speedup 1.0000x reference)
//
#include <hip/hip_runtime.h>

#define NNODES 50000
#define NEDGES 250000
#define NTYPES 3
#define SCAN_B ((NNODES + 255) / 256)   // 196 blocks per etype
#define LSTR 40                          // LDS row stride in shorts (80B, 16B-aligned b128)

typedef __attribute__((ext_vector_type(8))) short bf16x8;
typedef __attribute__((ext_vector_type(4))) float f32x4;

__device__ __forceinline__ float lrelu(float x, float s) { return x >= 0.f ? x : s * x; }

__device__ __forceinline__ unsigned short bf16_rne(float f) {
    unsigned u = __float_as_uint(f);
    unsigned r = (u + 0x7fffu + ((u >> 16) & 1u)) >> 16;
    return (unsigned short)r;
}
__device__ __forceinline__ float bf16_to_f(unsigned short h) {
    return __uint_as_float((unsigned)h << 16);
}

// ---------------------------------------------------------------- build x -> bf16 hi/lo (K padded to 64)
__global__ void build_x_kernel(const int* __restrict__ cat, const float* __restrict__ cont,
                               const float* __restrict__ e0, const float* __restrict__ e1,
                               const float* __restrict__ e2, short* __restrict__ Ahi,
                               short* __restrict__ Alo) {
    int n = blockIdx.x * 4 + (threadIdx.x >> 6);
    int k = threadIdx.x & 63;
    if (n >= NNODES) return;
    float v = 0.f;
    if (k < 8) v = e0[cat[n * 3 + 0] * 8 + k];
    else if (k < 11) v = e1[cat[n * 3 + 1] * 3 + (k - 8)];
    else if (k < 17) v = e2[cat[n * 3 + 2] * 6 + (k - 11)];
    else if (k < 34) v = cont[n * 17 + (k - 17)];
    unsigned short h = bf16_rne(v);
    float fh = bf16_to_f(h);
    unsigned short l = bf16_rne(v - fh);
    Ahi[(size_t)n * 64 + k] = (short)h;
    Alo[(size_t)n * 64 + k] = (short)l;
}

// ---------------------------------------------------------------- CSR build
__global__ void hist_kernel(const int* __restrict__ dst, int* __restrict__ deg) {
    int idx = blockIdx.x * blockDim.x + threadIdx.x;
    if (idx >= NTYPES * NEDGES) return;
    int t = idx / NEDGES;
    atomicAdd(&deg[t * NNODES + dst[idx]], 1);
}

__global__ void scan1_kernel(const int* __restrict__ deg, int* __restrict__ rowptr,
                             int* __restrict__ bsum) {
    __shared__ int sd[256];
    int t = blockIdx.y, b = blockIdx.x, tid = threadIdx.x;
    int n = b * 256 + tid;
    int v = (n < NNODES) ? deg[t * NNODES + n] : 0;
    sd[tid] = v;
    __syncthreads();
    for (int off = 1; off < 256; off <<= 1) {
        int x = 0;
        if (tid >= off) x = sd[tid - off];
        __syncthreads();
        if (tid >= off) sd[tid] += x;
        __syncthreads();
    }
    int incl = sd[tid];
    if (n < NNODES) rowptr[(size_t)t * (NNODES + 1) + n] = incl - v;  // exclusive
    if (tid == 255) bsum[t * SCAN_B + b] = incl;
}

__global__ void scan2_kernel(int* __restrict__ bsum, int* __restrict__ rowptr) {
    int t = threadIdx.x;
    if (t >= NTYPES) return;
    int run = 0;
    for (int i = 0; i < SCAN_B; i++) {
        int v = bsum[t * SCAN_B + i];
        bsum[t * SCAN_B + i] = run;
        run += v;
    }
    rowptr[(size_t)t * (NNODES + 1) + NNODES] = run;
}

__global__ void scan3_kernel(const int* __restrict__ bsum, int* __restrict__ rowptr) {
    int t = blockIdx.y, b = blockIdx.x;
    int n = b * 256 + threadIdx.x;
    if (n < NNODES) rowptr[(size_t)t * (NNODES + 1) + n] += bsum[t * SCAN_B + b];
}

// combined per-node etype block starts: cbase4[n] = {start_t0, start_t1, start_t2, end}
__global__ void cbase_kernel(const int* __restrict__ rowptr, int4* __restrict__ cbase4) {
    int n = blockIdx.x * blockDim.x + threadIdx.x;
    if (n >= NNODES) return;
    int r0 = rowptr[n], r0e = rowptr[n + 1];
    int r1 = rowptr[(NNODES + 1) + n], r1e = rowptr[(NNODES + 1) + n + 1];
    int r2 = rowptr[2 * (NNODES + 1) + n], r2e = rowptr[2 * (NNODES + 1) + n + 1];
    int b0 = r0 + r1 + r2;
    int b1 = b0 + (r0e - r0);
    int b2 = b1 + (r1e - r1);
    int b3 = b2 + (r2e - r2);
    cbase4[n] = (int4){b0, b1, b2, b3};
}

__global__ void scatter_kernel(const int* __restrict__ src, const int* __restrict__ dst,
                               const int* __restrict__ cbase, int* __restrict__ cursor,
                               int* __restrict__ csrc_c) {
    int idx = blockIdx.x * blockDim.x + threadIdx.x;
    if (idx >= NTYPES * NEDGES) return;
    int t = idx / NEDGES;
    int s = src[idx], d = dst[idx];
    int pos = cbase[(size_t)d * 4 + t] + atomicAdd(&cursor[t * NNODES + d], 1);
    csrc_c[pos] = t * NNODES + s;
}

// ---------------------------------------------------------------- W -> transposed bf16 hi/lo
__global__ void convert_B_kernel(const float* __restrict__ W, short* __restrict__ Bhi,
                                 short* __restrict__ Blo, int Kin, int Kout, int HD, int Mfeat) {
    int idx = blockIdx.x * blockDim.x + threadIdx.x;
    if (idx >= Mfeat * Kout) return;
    int m = idx / Kout, k = idx % Kout;
    int t = m / HD, j = m % HD;
    float a = (k < Kin) ? W[((size_t)t * Kin + k) * HD + j] : 0.f;
    unsigned short h = bf16_rne(a);
    float fh = bf16_to_f(h);
    unsigned short l = bf16_rne(a - fh);
    Bhi[(size_t)m * Kout + k] = (short)h;
    Blo[(size_t)m * Kout + k] = (short)l;
}

// el/er as extra B columns: row Mfeat + t*8 + r; r=0..2 el heads, r=4..6 er heads.
__global__ void convert_Bel_kernel(const float* __restrict__ W, const float* __restrict__ alw,
                                   const float* __restrict__ arw, short* __restrict__ Bhi,
                                   short* __restrict__ Blo, int Kin, int Kout, int H, int D,
                                   int Mfeat) {
    int idx = blockIdx.x * blockDim.x + threadIdx.x;
    if (idx >= 24 * Kout) return;
    int m = idx / Kout, k = idx % Kout;
    int t = m >> 3, r = m & 7;
    int h = r & 3;
    float v = 0.f;
    if (h < H && k < Kin) {
        const float* a = ((r >= 4) ? arw : alw) + ((size_t)t * H + h) * D;
        const float* w = W + ((size_t)t * Kin + k) * (H * D) + h * D;
        for (int j = 0; j < D; j++) v += w[j] * a[j];
    }
    unsigned short hh = bf16_rne(v);
    float fh = bf16_to_f(hh);
    unsigned short ll = bf16_rne(v - fh);
    size_t o = (size_t)(Mfeat + m) * Kout + k;
    Bhi[o] = (short)hh;
    Blo[o] = (short)ll;
}

// ---------------------------------------------------------------- bf16x3 MFMA GEMM (round-10 proven)
__global__ __launch_bounds__(256) void gemm_mfma_kernel(
    const short* __restrict__ AhiG, const short* __restrict__ AloG,
    const short* __restrict__ BhiG, const short* __restrict__ BloG,
    unsigned short* __restrict__ feat, float* __restrict__ elr, int N, int K, int M, int Mfeat,
    int HD, size_t tstride, int MT) {
    __shared__ short smem[4 * 128 * LSTR];  // 40,960 B
    short* AsH = smem;
    short* AsL = smem + 128 * LSTR;
    short* BsH = smem + 2 * 128 * LSTR;
    short* BsL = smem + 3 * 128 * LSTR;
    int tid = threadIdx.x;

    // bijective XCD swizzle (8 XCDs, round-robin dispatch)
    int nwg = gridDim.x;
    int q = nwg >> 3, rr = nwg & 7;
    int xx = blockIdx.x & 7, ii = blockIdx.x >> 3;
    int wg = (xx < rr ? xx * (q + 1) : rr * (q + 1) + (xx - rr) * q) + ii;
    int m0 = (wg % MT) * 128, n0 = (wg / MT) * 128;

    int wid = tid >> 6, lane = tid & 63;
    int wm = (wid >> 1) * 64, wn = (wid & 1) * 64;
    int lrow = lane & 15, kq = (lane >> 4) * 8;
    int sr = tid >> 2;
    int skq = (tid & 3) * 8;
    f32x4 acc[4][4] = {};

    for (int k0 = 0; k0 < K; k0 += 32) {
        __syncthreads();
#pragma unroll
        for (int p = 0; p < 2; p++) {
            const bf16x8 z = {};
            bf16x8 vh = z, vl = z;
            int gr = n0 + sr + p * 64;
            if (gr < N) {
                size_t o = (size_t)gr * K + k0 + skq;
                vh = *(const bf16x8*)(AhiG + o);
                vl = *(const bf16x8*)(AloG + o);
            }
            *(bf16x8*)&AsH[(sr + p * 64) * LSTR + skq] = vh;
            *(bf16x8*)&AsL[(sr + p * 64) * LSTR + skq] = vl;
            vh = z;
            vl = z;
            int gc = m0 + sr + p * 64;
            if (gc < M) {
                size_t o = (size_t)gc * K + k0 + skq;
                vh = *(const bf16x8*)(BhiG + o);
                vl = *(const bf16x8*)(BloG + o);
            }
            *(bf16x8*)&BsH[(sr + p * 64) * LSTR + skq] = vh;
            *(bf16x8*)&BsL[(sr + p * 64) * LSTR + skq] = vl;
        }
        __syncthreads();
        bf16x8 ah[4], al[4], bh[4], bl[4];
#pragma unroll
        for (int f = 0; f < 4; f++) {
            int ra = (wm + f * 16 + lrow) * LSTR + kq;
            ah[f] = *(const bf16x8*)&AsH[ra];
            al[f] = *(const bf16x8*)&AsL[ra];
            int rb = (wn + f * 16 + lrow) * LSTR + kq;
            bh[f] = *(const bf16x8*)&BsH[rb];
            bl[f] = *(const bf16x8*)&BsL[rb];
        }
#pragma unroll
        for (int fa = 0; fa < 4; fa++)
#pragma unroll
            for (int fb = 0; fb < 4; fb++) {
                acc[fa][fb] =
                    __builtin_amdgcn_mfma_f32_16x16x32_bf16(al[fa], bh[fb], acc[fa][fb], 0, 0, 0);
                acc[fa][fb] =
                    __builtin_amdgcn_mfma_f32_16x16x32_bf16(ah[fa], bl[fb], acc[fa][fb], 0, 0, 0);
                acc[fa][fb] =
                    __builtin_amdgcn_mfma_f32_16x16x32_bf16(ah[fa], bh[fb], acc[fa][fb], 0, 0, 0);
            }
    }

    // ---- epilogue: elr cols straight from regs; feat via LDS transpose.
    __syncthreads();
    short* Ct = smem;  // 128 x 136 shorts
#pragma unroll
    for (int fb = 0; fb < 4; fb++) {
        int col = wn + fb * 16 + lrow;
        int gc = m0 + col;
#pragma unroll
        for (int fa = 0; fa < 4; fa++) {
            int rbase = wm + fa * 16 + (lane >> 4) * 4;
#pragma unroll
            for (int e = 0; e < 4; e++) {
                Ct[(rbase + e) * 136 + col] = (short)bf16_rne(acc[fa][fb][e]);
                if (gc >= Mfeat && gc < M) {
                    int gr = n0 + rbase + e;
                    if (gr < N) {
                        int m = gc - Mfeat;
                        int t = m >> 3, r = m & 7;
                        elr[((size_t)t * N + gr) * 8 + r] = acc[fa][fb][e];
                    }
                }
            }
        }
    }
    __syncthreads();
    int row = tid >> 1, half = tid & 1;
    int gr = n0 + row;
    if (gr < N) {
#pragma unroll
        for (int p = 0; p < 4; p++) {
            int col0 = half * 64 + p * 16;
            int gc0 = m0 + col0;
            if (gc0 < Mfeat) {
                int t = gc0 / HD, j = gc0 - t * HD;
                bf16x8 v0 = *(const bf16x8*)&Ct[row * 136 + col0];
                bf16x8 v1 = *(const bf16x8*)&Ct[row * 136 + col0 + 8];
                unsigned short* dp = feat + (size_t)t * tstride + (size_t)gr * HD + j;
                *(bf16x8*)dp = v0;
                *(bf16x8*)(dp + 8) = v1;
            }
        }
    }
}

// ---------------------------------------------------------------- per-edge raw attention weights
// thread per (etype,node): w = exp(lrelu(el[s]+er[d],0.2)) stored in combined CSR
// order; inv_den per (node,etype,head) stored separately (normalization deferred
// to agg: (sum w*feat) * inv_den == sum (w/den)*feat).
template <int H>
__global__ void alpha_kernel(const int4* __restrict__ cbase4, const int* __restrict__ csrc_c,
                             const float* __restrict__ elr, float* __restrict__ alpha_c,
                             float4* __restrict__ invden4) {
    int idx = blockIdx.x * blockDim.x + threadIdx.x;
    if (idx >= NTYPES * NNODES) return;
    int t = idx / NNODES, node = idx - t * NNODES;
    int4 cb = cbase4[node];
    int rs = (t == 0) ? cb.x : (t == 1) ? cb.y : cb.z;
    int re = (t == 0) ? cb.y : (t == 1) ? cb.z : cb.w;
    float4 er4 = *(const float4*)(elr + ((size_t)t * NNODES + node) * 8 + 4);
    float erd[3] = {er4.x, er4.y, er4.z};
    float den[H];
#pragma unroll
    for (int h = 0; h < H; h++) den[h] = 0.f;
    for (int k = rs; k < re; k++) {
        int cs = csrc_c[k];  // = t*N + s
        float4 e4 = *(const float4*)(elr + (size_t)cs * 8);
        float ev[3] = {e4.x, e4.y, e4.z};
        float w[3] = {0.f, 0.f, 0.f};
#pragma unroll
        for (int h = 0; h < H; h++) {
            w[h] = __expf(lrelu(ev[h] + erd[h], 0.2f));
            den[h] += w[h];
        }
        if (H == 1)
            alpha_c[k] = w[0];
        else
            *(float4*)(alpha_c + (size_t)k * 4) = (float4){w[0], w[1], w[2], 0.f};
    }
    float4 iv = {0.f, 0.f, 0.f, 0.f};
    if (re > rs) {
        iv.x = __frcp_rn(den[0]);
        if (H > 1) {
            iv.y = __frcp_rn(den[1]);
            iv.z = __frcp_rn(den[2]);
        }
    }
    invden4[idx] = iv;
}

// ---------------------------------------------------------------- fused combined-CSR aggregate
// D=64: wave per node (EL=3). D=32: 2 nodes per wave (lanes 0-31 / 32-63).
// One chunked loop over all etypes' edges; per-etype accumulators; normalization
// + bias + lrelu + mean in epilogue.
template <int H, int D, int BF16OUT>
__global__ __launch_bounds__(256) void gat_agg_kernel(
    const int4* __restrict__ cbase4, const int* __restrict__ csrc_c,
    const float* __restrict__ alpha_c, const float4* __restrict__ invden4,
    const unsigned short* __restrict__ feat_all, const float* __restrict__ b_all,
    float* __restrict__ fout, short* __restrict__ Ahi, short* __restrict__ Alo) {
    constexpr int HD = H * D;
    constexpr int LPN = (D == 64) ? 64 : 32;  // lanes per node
    constexpr int NPW = 64 / LPN;             // nodes per wave
    constexpr int EL = HD / LPN;
    int lane = threadIdx.x & 63;
    int j0 = lane & (LPN - 1);
    int node = blockIdx.x * (4 * NPW) + (threadIdx.x >> 6) * NPW + ((NPW == 2) ? (lane >> 5) : 0);
    if (node >= NNODES) return;
    int4 cb = cbase4[node];
    int ks = cb.x, ke = cb.w;
    float acc[3][EL] = {};
    for (int it = 0;; ++it) {
        int k = ks + it * 4;
        if (!__ballot(k < ke)) break;
        int cnt = ke - k;  // may be <= 0 for this node's half
        int cs[4];
        float4 w4[4];
#pragma unroll
        for (int c = 0; c < 4; c++) {
            int kk = (c < cnt) ? (k + c) : min(ks, NTYPES * NEDGES - 1);
            cs[c] = csrc_c[kk];
            if (H == 1) {
                float wv = (c < cnt) ? alpha_c[kk] : 0.f;
                w4[c] = (float4){wv, 0.f, 0.f, 0.f};
            } else {
                w4[c] = (c < cnt) ? *(const float4*)(alpha_c + (size_t)kk * 4)
                                  : (float4){0.f, 0.f, 0.f, 0.f};
            }
        }
#pragma unroll
        for (int c = 0; c < 4; c++) {
            int t = (cs[c] >= NNODES) + (cs[c] >= 2 * NNODES);
            float wq[3] = {w4[c].x, w4[c].y, w4[c].z};
            float fv[EL];
#pragma unroll
            for (int q = 0; q < EL; q++)
                fv[q] = bf16_to_f(feat_all[(size_t)cs[c] * HD + j0 + q * LPN]);
            if (t == 0) {
#pragma unroll
                for (int q = 0; q < EL; q++)
                    acc[0][q] = fmaf((D == 64) ? wq[q] : wq[0], fv[q], acc[0][q]);
            } else if (t == 1) {
#pragma unroll
                for (int q = 0; q < EL; q++)
                    acc[1][q] = fmaf((D == 64) ? wq[q] : wq[0], fv[q], acc[1][q]);
            } else {
#pragma unroll
                for (int q = 0; q < EL; q++)
                    acc[2][q] = fmaf((D == 64) ? wq[q] : wq[0], fv[q], acc[2][q]);
            }
        }
    }
    float out[EL] = {};
#pragma unroll
    for (int t = 0; t < 3; t++) {
        float4 iv = invden4[(size_t)t * NNODES + node];
        float ivq[3] = {iv.x, iv.y, iv.z};
#pragma unroll
        for (int q = 0; q < EL; q++) {
            int j = j0 + q * LPN;
            float v = acc[t][q] * ((D == 64) ? ivq[q] : ivq[0]);
            v = lrelu(v + b_all[t * HD + j], 0.01f);
            out[q] += v * (1.f / 3.f);
        }
    }
#pragma unroll
    for (int q = 0; q < EL; q++) {
        int j = j0 + q * LPN;
        if (BF16OUT) {
            unsigned short h = bf16_rne(out[q]);
            float fh = bf16_to_f(h);
            unsigned short l = bf16_rne(out[q] - fh);
            Ahi[(size_t)node * HD + j] = (short)h;
            Alo[(size_t)node * HD + j] = (short)l;
        } else {
            fout[(size_t)node * HD + j] = out[q];
        }
    }
}

extern "C" void kernel_launch(void* const* d_in, const int* in_sizes, int n_in, void* d_out,
                              int out_size, void* d_ws, size_t ws_size, hipStream_t stream) {
    const int* cat = (const int*)d_in[0];
    const float* cont = (const float*)d_in[1];
    const int* src = (const int*)d_in[2];
    const int* dst = (const int*)d_in[3];
    const float* emb0 = (const float*)d_in[4];
    const float* emb1 = (const float*)d_in[5];
    const float* emb2 = (const float*)d_in[6];
    const float* W1 = (const float*)d_in[7];
    const float* al1 = (const float*)d_in[8];
    const float* ar1 = (const float*)d_in[9];
    const float* b1 = (const float*)d_in[10];
    const float* W2 = (const float*)d_in[11];
    const float* al2 = (const float*)d_in[12];
    const float* ar2 = (const float*)d_in[13];
    const float* b2 = (const float*)d_in[14];
    const float* W3 = (const float*)d_in[15];
    const float* al3 = (const float*)d_in[16];
    const float* ar3 = (const float*)d_in[17];
    const float* b3 = (const float*)d_in[18];

    unsigned short* feat_all = (unsigned short*)d_ws;                // 3*N*192 bf16
    short* Ahi = (short*)(feat_all + (size_t)3 * NNODES * 192);      // N*192 bf16
    short* Alo = Ahi + (size_t)NNODES * 192;
    short* Bhi = Alo + (size_t)NNODES * 192;                         // 600*192 bf16
    short* Blo = Bhi + 600 * 192;
    float* elr = (float*)(Blo + 600 * 192);                          // 3*N*8 f32
    float* alpha_c = elr + (size_t)3 * NNODES * 8;                   // 3*E*4 f32 (combined)
    float4* invden4 = (float4*)(alpha_c + (size_t)3 * NEDGES * 4);   // 3*N float4
    int4* cbase4 = (int4*)(invden4 + (size_t)3 * NNODES);            // N int4
    int* rowptr = (int*)(cbase4 + NNODES);                           // 3*(N+1)
    int* csrc_c = rowptr + NTYPES * (NNODES + 1);                    // 3*E combined
    int* deg = csrc_c + NTYPES * NEDGES;                             // 3*N
    int* cursor = deg + NTYPES * NNODES;                             // 3*N
    int* bsum = cursor + NTYPES * NNODES;                            // 3*SCAN_B

    // ---- CSR build (combined layout, reused by all 3 layers)
    hipMemsetAsync(deg, 0, (size_t)NTYPES * NNODES * 4, stream);
    hipMemsetAsync(cursor, 0, (size_t)NTYPES * NNODES * 4, stream);
    hist_kernel<<<(NTYPES * NEDGES + 255) / 256, 256, 0, stream>>>(dst, deg);
    scan1_kernel<<<dim3(SCAN_B, NTYPES), 256, 0, stream>>>(deg, rowptr, bsum);
    scan2_kernel<<<1, 64, 0, stream>>>(bsum, rowptr);
    scan3_kernel<<<dim3(SCAN_B, NTYPES), 256, 0, stream>>>(bsum, rowptr);
    cbase_kernel<<<(NNODES + 255) / 256, 256, 0, stream>>>(rowptr, cbase4);
    scatter_kernel<<<(NTYPES * NEDGES + 255) / 256, 256, 0, stream>>>(src, dst, (const int*)cbase4,
                                                                      cursor, csrc_c);

    build_x_kernel<<<(NNODES + 3) / 4, 256, 0, stream>>>(cat, cont, emb0, emb1, emb2, Ahi, Alo);

    const int gy = (NNODES + 127) / 128;  // 391
    const int nb = (NTYPES * NNODES + 255) / 256;
    const int aggb64 = (NNODES + 3) / 4;   // wave per node
    const int aggb32 = (NNODES + 7) / 8;   // 2 nodes per wave

    // ---- layer 1: K=34->64, Mfeat=576
    convert_B_kernel<<<(576 * 64 + 255) / 256, 256, 0, stream>>>(W1, Bhi, Blo, 34, 64, 192, 576);
    convert_Bel_kernel<<<(24 * 64 + 255) / 256, 256, 0, stream>>>(W1, al1, ar1, Bhi, Blo, 34, 64, 3,
                                                                  64, 576);
    gemm_mfma_kernel<<<5 * gy, 256, 0, stream>>>(Ahi, Alo, Bhi, Blo, feat_all, elr, NNODES, 64, 600,
                                                 576, 192, (size_t)NNODES * 192, 5);
    alpha_kernel<3><<<nb, 256, 0, stream>>>(cbase4, csrc_c, elr, alpha_c, invden4);
    gat_agg_kernel<3, 64, 1><<<aggb64, 256, 0, stream>>>(cbase4, csrc_c, alpha_c, invden4, feat_all,
                                                         b1, nullptr, Ahi, Alo);

    // ---- layer 2: K=192, Mfeat=576
    convert_B_kernel<<<(576 * 192 + 255) / 256, 256, 0, stream>>>(W2, Bhi, Blo, 192, 192, 192, 576);
    convert_Bel_kernel<<<(24 * 192 + 255) / 256, 256, 0, stream>>>(W2, al2, ar2, Bhi, Blo, 192, 192,
                                                                   3, 64, 576);
    gemm_mfma_kernel<<<5 * gy, 256, 0, stream>>>(Ahi, Alo, Bhi, Blo, feat_all, elr, NNODES, 192,
                                                 600, 576, 192, (size_t)NNODES * 192, 5);
    alpha_kernel<3><<<nb, 256, 0, stream>>>(cbase4, csrc_c, elr, alpha_c, invden4);
    gat_agg_kernel<3, 64, 1><<<aggb64, 256, 0, stream>>>(cbase4, csrc_c, alpha_c, invden4, feat_all,
                                                         b2, nullptr, Ahi, Alo);

    // ---- layer 3: K=192, Mfeat=96 -> d_out (fp32)
    convert_B_kernel<<<(96 * 192 + 255) / 256, 256, 0, stream>>>(W3, Bhi, Blo, 192, 192, 32, 96);
    convert_Bel_kernel<<<(24 * 192 + 255) / 256, 256, 0, stream>>>(W3, al3, ar3, Bhi, Blo, 192, 192,
                                                                   1, 32, 96);
    gemm_mfma_kernel<<<1 * gy, 256, 0, stream>>>(Ahi, Alo, Bhi, Blo, feat_all, elr, NNODES, 192,
                                                 120, 96, 32, (size_t)NNODES * 32, 1);
    alpha_kernel<1><<<nb, 256, 0, stream>>>(cbase4, csrc_c, elr, alpha_c, invden4);
    gat_agg_kernel<1, 32, 0><<<aggb32, 256, 0, stream>>>(cbase4, csrc_c, alpha_c, invden4, feat_all,
                                                         b3, (float*)d_out, nullptr, nullptr);
}

// Round 12
// 472.677 us; speedup vs baseline: 1.1834x; 1.1834x over previous
//
#include <hip/hip_runtime.h>

#define NNODES 50000
#define NEDGES 250000
#define NTYPES 3
#define SCAN_B ((NNODES + 255) / 256)   // 196 blocks per etype
#define LSTR 40                          // LDS row stride in shorts (80B, 16B-aligned b128)

typedef __attribute__((ext_vector_type(8))) short bf16x8;
typedef __attribute__((ext_vector_type(4))) float f32x4;

__device__ __forceinline__ float lrelu(float x, float s) { return x >= 0.f ? x : s * x; }

__device__ __forceinline__ unsigned short bf16_rne(float f) {
    unsigned u = __float_as_uint(f);
    unsigned r = (u + 0x7fffu + ((u >> 16) & 1u)) >> 16;
    return (unsigned short)r;
}
__device__ __forceinline__ float bf16_to_f(unsigned short h) {
    return __uint_as_float((unsigned)h << 16);
}

// ---------------------------------------------------------------- build x -> bf16 hi/lo (K padded to 64)
__global__ void build_x_kernel(const int* __restrict__ cat, const float* __restrict__ cont,
                               const float* __restrict__ e0, const float* __restrict__ e1,
                               const float* __restrict__ e2, short* __restrict__ Ahi,
                               short* __restrict__ Alo) {
    int n = blockIdx.x * 4 + (threadIdx.x >> 6);
    int k = threadIdx.x & 63;
    if (n >= NNODES) return;
    float v = 0.f;
    if (k < 8) v = e0[cat[n * 3 + 0] * 8 + k];
    else if (k < 11) v = e1[cat[n * 3 + 1] * 3 + (k - 8)];
    else if (k < 17) v = e2[cat[n * 3 + 2] * 6 + (k - 11)];
    else if (k < 34) v = cont[n * 17 + (k - 17)];
    unsigned short h = bf16_rne(v);
    float fh = bf16_to_f(h);
    unsigned short l = bf16_rne(v - fh);
    Ahi[(size_t)n * 64 + k] = (short)h;
    Alo[(size_t)n * 64 + k] = (short)l;
}

// ---------------------------------------------------------------- CSR build
__global__ void hist_kernel(const int* __restrict__ dst, int* __restrict__ deg) {
    int idx = blockIdx.x * blockDim.x + threadIdx.x;
    if (idx >= NTYPES * NEDGES) return;
    int t = idx / NEDGES;
    atomicAdd(&deg[t * NNODES + dst[idx]], 1);
}

__global__ void scan1_kernel(const int* __restrict__ deg, int* __restrict__ rowptr,
                             int* __restrict__ bsum) {
    __shared__ int sd[256];
    int t = blockIdx.y, b = blockIdx.x, tid = threadIdx.x;
    int n = b * 256 + tid;
    int v = (n < NNODES) ? deg[t * NNODES + n] : 0;
    sd[tid] = v;
    __syncthreads();
    for (int off = 1; off < 256; off <<= 1) {
        int x = 0;
        if (tid >= off) x = sd[tid - off];
        __syncthreads();
        if (tid >= off) sd[tid] += x;
        __syncthreads();
    }
    int incl = sd[tid];
    if (n < NNODES) rowptr[(size_t)t * (NNODES + 1) + n] = incl - v;  // exclusive
    if (tid == 255) bsum[t * SCAN_B + b] = incl;
}

__global__ void scan2_kernel(int* __restrict__ bsum, int* __restrict__ rowptr) {
    int t = threadIdx.x;
    if (t >= NTYPES) return;
    int run = 0;
    for (int i = 0; i < SCAN_B; i++) {
        int v = bsum[t * SCAN_B + i];
        bsum[t * SCAN_B + i] = run;
        run += v;
    }
    rowptr[(size_t)t * (NNODES + 1) + NNODES] = run;
}

__global__ void scan3_kernel(const int* __restrict__ bsum, int* __restrict__ rowptr) {
    int t = blockIdx.y, b = blockIdx.x;
    int n = b * 256 + threadIdx.x;
    if (n < NNODES) rowptr[(size_t)t * (NNODES + 1) + n] += bsum[t * SCAN_B + b];
}

__global__ void scatter_kernel(const int* __restrict__ src, const int* __restrict__ dst,
                               const int* __restrict__ rowptr, int* __restrict__ cursor,
                               int* __restrict__ csrc) {
    int idx = blockIdx.x * blockDim.x + threadIdx.x;
    if (idx >= NTYPES * NEDGES) return;
    int t = idx / NEDGES;
    int s = src[idx], d = dst[idx];
    int pos = rowptr[(size_t)t * (NNODES + 1) + d] + atomicAdd(&cursor[t * NNODES + d], 1);
    csrc[(size_t)t * NEDGES + pos] = s;
}

// ---------------------------------------------------------------- W -> transposed bf16 hi/lo
__global__ void convert_B_kernel(const float* __restrict__ W, short* __restrict__ Bhi,
                                 short* __restrict__ Blo, int Kin, int Kout, int HD, int Mfeat) {
    int idx = blockIdx.x * blockDim.x + threadIdx.x;
    if (idx >= Mfeat * Kout) return;
    int m = idx / Kout, k = idx % Kout;
    int t = m / HD, j = m % HD;
    float a = (k < Kin) ? W[((size_t)t * Kin + k) * HD + j] : 0.f;
    unsigned short h = bf16_rne(a);
    float fh = bf16_to_f(h);
    unsigned short l = bf16_rne(a - fh);
    Bhi[(size_t)m * Kout + k] = (short)h;
    Blo[(size_t)m * Kout + k] = (short)l;
}

// el/er as extra B columns: row Mfeat + t*8 + r; r=0..2 el heads, r=4..6 er heads.
__global__ void convert_Bel_kernel(const float* __restrict__ W, const float* __restrict__ alw,
                                   const float* __restrict__ arw, short* __restrict__ Bhi,
                                   short* __restrict__ Blo, int Kin, int Kout, int H, int D,
                                   int Mfeat) {
    int idx = blockIdx.x * blockDim.x + threadIdx.x;
    if (idx >= 24 * Kout) return;
    int m = idx / Kout, k = idx % Kout;
    int t = m >> 3, r = m & 7;
    int h = r & 3;
    float v = 0.f;
    if (h < H && k < Kin) {
        const float* a = ((r >= 4) ? arw : alw) + ((size_t)t * H + h) * D;
        const float* w = W + ((size_t)t * Kin + k) * (H * D) + h * D;
        for (int j = 0; j < D; j++) v += w[j] * a[j];
    }
    unsigned short hh = bf16_rne(v);
    float fh = bf16_to_f(hh);
    unsigned short ll = bf16_rne(v - fh);
    size_t o = (size_t)(Mfeat + m) * Kout + k;
    Bhi[o] = (short)hh;
    Blo[o] = (short)ll;
}

// ---------------------------------------------------------------- bf16x3 MFMA GEMM (round-10 proven)
__global__ __launch_bounds__(256) void gemm_mfma_kernel(
    const short* __restrict__ AhiG, const short* __restrict__ AloG,
    const short* __restrict__ BhiG, const short* __restrict__ BloG,
    unsigned short* __restrict__ feat, float* __restrict__ elr, int N, int K, int M, int Mfeat,
    int HD, size_t tstride, int MT) {
    __shared__ short smem[4 * 128 * LSTR];  // 40,960 B
    short* AsH = smem;
    short* AsL = smem + 128 * LSTR;
    short* BsH = smem + 2 * 128 * LSTR;
    short* BsL = smem + 3 * 128 * LSTR;
    int tid = threadIdx.x;

    // bijective XCD swizzle (8 XCDs, round-robin dispatch)
    int nwg = gridDim.x;
    int q = nwg >> 3, rr = nwg & 7;
    int xx = blockIdx.x & 7, ii = blockIdx.x >> 3;
    int wg = (xx < rr ? xx * (q + 1) : rr * (q + 1) + (xx - rr) * q) + ii;
    int m0 = (wg % MT) * 128, n0 = (wg / MT) * 128;

    int wid = tid >> 6, lane = tid & 63;
    int wm = (wid >> 1) * 64, wn = (wid & 1) * 64;
    int lrow = lane & 15, kq = (lane >> 4) * 8;
    int sr = tid >> 2;
    int skq = (tid & 3) * 8;
    f32x4 acc[4][4] = {};

    for (int k0 = 0; k0 < K; k0 += 32) {
        __syncthreads();
#pragma unroll
        for (int p = 0; p < 2; p++) {
            const bf16x8 z = {};
            bf16x8 vh = z, vl = z;
            int gr = n0 + sr + p * 64;
            if (gr < N) {
                size_t o = (size_t)gr * K + k0 + skq;
                vh = *(const bf16x8*)(AhiG + o);
                vl = *(const bf16x8*)(AloG + o);
            }
            *(bf16x8*)&AsH[(sr + p * 64) * LSTR + skq] = vh;
            *(bf16x8*)&AsL[(sr + p * 64) * LSTR + skq] = vl;
            vh = z;
            vl = z;
            int gc = m0 + sr + p * 64;
            if (gc < M) {
                size_t o = (size_t)gc * K + k0 + skq;
                vh = *(const bf16x8*)(BhiG + o);
                vl = *(const bf16x8*)(BloG + o);
            }
            *(bf16x8*)&BsH[(sr + p * 64) * LSTR + skq] = vh;
            *(bf16x8*)&BsL[(sr + p * 64) * LSTR + skq] = vl;
        }
        __syncthreads();
        bf16x8 ah[4], al[4], bh[4], bl[4];
#pragma unroll
        for (int f = 0; f < 4; f++) {
            int ra = (wm + f * 16 + lrow) * LSTR + kq;
            ah[f] = *(const bf16x8*)&AsH[ra];
            al[f] = *(const bf16x8*)&AsL[ra];
            int rb = (wn + f * 16 + lrow) * LSTR + kq;
            bh[f] = *(const bf16x8*)&BsH[rb];
            bl[f] = *(const bf16x8*)&BsL[rb];
        }
#pragma unroll
        for (int fa = 0; fa < 4; fa++)
#pragma unroll
            for (int fb = 0; fb < 4; fb++) {
                acc[fa][fb] =
                    __builtin_amdgcn_mfma_f32_16x16x32_bf16(al[fa], bh[fb], acc[fa][fb], 0, 0, 0);
                acc[fa][fb] =
                    __builtin_amdgcn_mfma_f32_16x16x32_bf16(ah[fa], bl[fb], acc[fa][fb], 0, 0, 0);
                acc[fa][fb] =
                    __builtin_amdgcn_mfma_f32_16x16x32_bf16(ah[fa], bh[fb], acc[fa][fb], 0, 0, 0);
            }
    }

    // ---- epilogue: elr cols straight from regs; feat via LDS transpose.
    __syncthreads();
    short* Ct = smem;  // 128 x 136 shorts
#pragma unroll
    for (int fb = 0; fb < 4; fb++) {
        int col = wn + fb * 16 + lrow;
        int gc = m0 + col;
#pragma unroll
        for (int fa = 0; fa < 4; fa++) {
            int rbase = wm + fa * 16 + (lane >> 4) * 4;
#pragma unroll
            for (int e = 0; e < 4; e++) {
                Ct[(rbase + e) * 136 + col] = (short)bf16_rne(acc[fa][fb][e]);
                if (gc >= Mfeat && gc < M) {
                    int gr = n0 + rbase + e;
                    if (gr < N) {
                        int m = gc - Mfeat;
                        int t = m >> 3, r = m & 7;
                        elr[((size_t)t * N + gr) * 8 + r] = acc[fa][fb][e];
                    }
                }
            }
        }
    }
    __syncthreads();
    int row = tid >> 1, half = tid & 1;
    int gr = n0 + row;
    if (gr < N) {
#pragma unroll
        for (int p = 0; p < 4; p++) {
            int col0 = half * 64 + p * 16;
            int gc0 = m0 + col0;
            if (gc0 < Mfeat) {
                int t = gc0 / HD, j = gc0 - t * HD;
                bf16x8 v0 = *(const bf16x8*)&Ct[row * 136 + col0];
                bf16x8 v1 = *(const bf16x8*)&Ct[row * 136 + col0 + 8];
                unsigned short* dp = feat + (size_t)t * tstride + (size_t)gr * HD + j;
                *(bf16x8*)dp = v0;
                *(bf16x8*)(dp + 8) = v1;
            }
        }
    }
}

// ---------------------------------------------------------------- per-edge raw attention weights
// thread per (etype,node), single pass: w = exp(lrelu(el[s]+er[d],0.2)) stored in
// per-etype CSR order; inv_den stored separately (normalization deferred to agg).
template <int H>
__global__ void alpha_kernel(const int* __restrict__ rowptr_all, const int* __restrict__ csrc_all,
                             const float* __restrict__ elr, float* __restrict__ alpha_all,
                             float4* __restrict__ invden4) {
    int idx = blockIdx.x * blockDim.x + threadIdx.x;
    if (idx >= NTYPES * NNODES) return;
    int t = idx / NNODES, node = idx - t * NNODES;
    const int* rowptr = rowptr_all + t * (NNODES + 1);
    const int* csrc = csrc_all + (size_t)t * NEDGES;
    const float* elr_t = elr + (size_t)t * NNODES * 8;
    float4 er4 = *(const float4*)(elr_t + (size_t)node * 8 + 4);
    float erd[3] = {er4.x, er4.y, er4.z};
    int rs = rowptr[node], re = rowptr[node + 1];
    float den[H];
#pragma unroll
    for (int h = 0; h < H; h++) den[h] = 0.f;
    for (int k = rs; k < re; k++) {
        int s = csrc[k];
        float4 e4 = *(const float4*)(elr_t + (size_t)s * 8);
        float ev[3] = {e4.x, e4.y, e4.z};
        float w[3] = {0.f, 0.f, 0.f};
#pragma unroll
        for (int h = 0; h < H; h++) {
            w[h] = __expf(lrelu(ev[h] + erd[h], 0.2f));
            den[h] += w[h];
        }
        if (H == 1)
            alpha_all[(size_t)t * NEDGES + k] = w[0];
        else
            *(float4*)(alpha_all + ((size_t)t * NEDGES + k) * 4) = (float4){w[0], w[1], w[2], 0.f};
    }
    float4 iv = {0.f, 0.f, 0.f, 0.f};
    if (re > rs) {
        iv.x = __frcp_rn(den[0]);
        if (H > 1) {
            iv.y = __frcp_rn(den[1]);
            iv.z = __frcp_rn(den[2]);
        }
    }
    invden4[idx] = iv;
}

// ---------------------------------------------------------------- fused per-etype aggregate
// D=64: wave per node (EL=3). D=32: 2 nodes per wave (lanes 0-31 / 32-63).
// Per-etype sequential loop (L2-friendly); deferred normalization in epilogue.
template <int H, int D, int BF16OUT>
__global__ __launch_bounds__(256) void gat_agg_kernel(
    const int* __restrict__ rowptr_all, const int* __restrict__ csrc_all,
    const float* __restrict__ alpha_all, const float4* __restrict__ invden4,
    const unsigned short* __restrict__ feat_all, const float* __restrict__ b_all,
    float* __restrict__ fout, short* __restrict__ Ahi, short* __restrict__ Alo) {
    constexpr int HD = H * D;
    constexpr int LPN = (D == 64) ? 64 : 32;  // lanes per node
    constexpr int NPW = 64 / LPN;             // nodes per wave
    constexpr int EL = HD / LPN;
    int lane = threadIdx.x & 63;
    int j0 = lane & (LPN - 1);
    int node = blockIdx.x * (4 * NPW) + (threadIdx.x >> 6) * NPW + ((NPW == 2) ? (lane >> 5) : 0);
    if (node >= NNODES) return;
    float out[EL] = {};
#pragma unroll 1
    for (int t = 0; t < NTYPES; t++) {
        const int* rowptr = rowptr_all + t * (NNODES + 1);
        const int* csrc = csrc_all + (size_t)t * NEDGES;
        const unsigned short* feat = feat_all + (size_t)t * NNODES * HD;
        int rs = rowptr[node], re = rowptr[node + 1];
        float acc[EL] = {};
        for (int k = rs; k < re; k += 4) {
            int cnt = re - k;
            int s[4];
            float4 w4[4];
#pragma unroll
            for (int c = 0; c < 4; c++) {
                int kk = k + (c < cnt ? c : 0);
                s[c] = csrc[kk];
                if (H == 1) {
                    float wv = alpha_all[(size_t)t * NEDGES + kk];
                    w4[c] = (float4){(c < cnt) ? wv : 0.f, 0.f, 0.f, 0.f};
                } else {
                    w4[c] = (c < cnt) ? *(const float4*)(alpha_all + ((size_t)t * NEDGES + kk) * 4)
                                      : (float4){0.f, 0.f, 0.f, 0.f};
                }
            }
#pragma unroll
            for (int c = 0; c < 4; c++) {
                float wq[3] = {w4[c].x, w4[c].y, w4[c].z};
#pragma unroll
                for (int q = 0; q < EL; q++) {
                    float fv = bf16_to_f(feat[(size_t)s[c] * HD + j0 + q * LPN]);
                    acc[q] = fmaf((D == 64) ? wq[q] : wq[0], fv, acc[q]);
                }
            }
        }
        float4 iv = invden4[(size_t)t * NNODES + node];
        float ivq[3] = {iv.x, iv.y, iv.z};
#pragma unroll
        for (int q = 0; q < EL; q++) {
            int j = j0 + q * LPN;
            float v = acc[q] * ((D == 64) ? ivq[q] : ivq[0]);
            v = lrelu(v + b_all[t * HD + j], 0.01f);
            out[q] += v * (1.f / 3.f);
        }
    }
#pragma unroll
    for (int q = 0; q < EL; q++) {
        int j = j0 + q * LPN;
        if (BF16OUT) {
            unsigned short h = bf16_rne(out[q]);
            float fh = bf16_to_f(h);
            unsigned short l = bf16_rne(out[q] - fh);
            Ahi[(size_t)node * HD + j] = (short)h;
            Alo[(size_t)node * HD + j] = (short)l;
        } else {
            fout[(size_t)node * HD + j] = out[q];
        }
    }
}

extern "C" void kernel_launch(void* const* d_in, const int* in_sizes, int n_in, void* d_out,
                              int out_size, void* d_ws, size_t ws_size, hipStream_t stream) {
    const int* cat = (const int*)d_in[0];
    const float* cont = (const float*)d_in[1];
    const int* src = (const int*)d_in[2];
    const int* dst = (const int*)d_in[3];
    const float* emb0 = (const float*)d_in[4];
    const float* emb1 = (const float*)d_in[5];
    const float* emb2 = (const float*)d_in[6];
    const float* W1 = (const float*)d_in[7];
    const float* al1 = (const float*)d_in[8];
    const float* ar1 = (const float*)d_in[9];
    const float* b1 = (const float*)d_in[10];
    const float* W2 = (const float*)d_in[11];
    const float* al2 = (const float*)d_in[12];
    const float* ar2 = (const float*)d_in[13];
    const float* b2 = (const float*)d_in[14];
    const float* W3 = (const float*)d_in[15];
    const float* al3 = (const float*)d_in[16];
    const float* ar3 = (const float*)d_in[17];
    const float* b3 = (const float*)d_in[18];

    unsigned short* feat_all = (unsigned short*)d_ws;                // 3*N*192 bf16
    short* Ahi = (short*)(feat_all + (size_t)3 * NNODES * 192);      // N*192 bf16
    short* Alo = Ahi + (size_t)NNODES * 192;
    short* Bhi = Alo + (size_t)NNODES * 192;                         // 600*192 bf16
    short* Blo = Bhi + 600 * 192;
    float* elr = (float*)(Blo + 600 * 192);                          // 3*N*8 f32
    float* alpha_all = elr + (size_t)3 * NNODES * 8;                 // 3*E*4 f32
    float4* invden4 = (float4*)(alpha_all + (size_t)3 * NEDGES * 4); // 3*N float4
    int* rowptr = (int*)(invden4 + (size_t)3 * NNODES);              // 3*(N+1)
    int* csrc = rowptr + NTYPES * (NNODES + 1);                      // 3*E
    int* deg = csrc + NTYPES * NEDGES;                               // 3*N
    int* cursor = deg + NTYPES * NNODES;                             // 3*N
    int* bsum = cursor + NTYPES * NNODES;                            // 3*SCAN_B

    // ---- CSR build (reused by all 3 layers)
    hipMemsetAsync(deg, 0, (size_t)NTYPES * NNODES * 4, stream);
    hipMemsetAsync(cursor, 0, (size_t)NTYPES * NNODES * 4, stream);
    hist_kernel<<<(NTYPES * NEDGES + 255) / 256, 256, 0, stream>>>(dst, deg);
    scan1_kernel<<<dim3(SCAN_B, NTYPES), 256, 0, stream>>>(deg, rowptr, bsum);
    scan2_kernel<<<1, 64, 0, stream>>>(bsum, rowptr);
    scan3_kernel<<<dim3(SCAN_B, NTYPES), 256, 0, stream>>>(bsum, rowptr);
    scatter_kernel<<<(NTYPES * NEDGES + 255) / 256, 256, 0, stream>>>(src, dst, rowptr, cursor,
                                                                      csrc);

    build_x_kernel<<<(NNODES + 3) / 4, 256, 0, stream>>>(cat, cont, emb0, emb1, emb2, Ahi, Alo);

    const int gy = (NNODES + 127) / 128;  // 391
    const int nb = (NTYPES * NNODES + 255) / 256;
    const int aggb64 = (NNODES + 3) / 4;   // wave per node
    const int aggb32 = (NNODES + 7) / 8;   // 2 nodes per wave

    // ---- layer 1: K=34->64, Mfeat=576
    convert_B_kernel<<<(576 * 64 + 255) / 256, 256, 0, stream>>>(W1, Bhi, Blo, 34, 64, 192, 576);
    convert_Bel_kernel<<<(24 * 64 + 255) / 256, 256, 0, stream>>>(W1, al1, ar1, Bhi, Blo, 34, 64, 3,
                                                                  64, 576);
    gemm_mfma_kernel<<<5 * gy, 256, 0, stream>>>(Ahi, Alo, Bhi, Blo, feat_all, elr, NNODES, 64, 600,
                                                 576, 192, (size_t)NNODES * 192, 5);
    alpha_kernel<3><<<nb, 256, 0, stream>>>(rowptr, csrc, elr, alpha_all, invden4);
    gat_agg_kernel<3, 64, 1><<<aggb64, 256, 0, stream>>>(rowptr, csrc, alpha_all, invden4, feat_all,
                                                         b1, nullptr, Ahi, Alo);

    // ---- layer 2: K=192, Mfeat=576
    convert_B_kernel<<<(576 * 192 + 255) / 256, 256, 0, stream>>>(W2, Bhi, Blo, 192, 192, 192, 576);
    convert_Bel_kernel<<<(24 * 192 + 255) / 256, 256, 0, stream>>>(W2, al2, ar2, Bhi, Blo, 192, 192,
                                                                   3, 64, 576);
    gemm_mfma_kernel<<<5 * gy, 256, 0, stream>>>(Ahi, Alo, Bhi, Blo, feat_all, elr, NNODES, 192,
                                                 600, 576, 192, (size_t)NNODES * 192, 5);
    alpha_kernel<3><<<nb, 256, 0, stream>>>(rowptr, csrc, elr, alpha_all, invden4);
    gat_agg_kernel<3, 64, 1><<<aggb64, 256, 0, stream>>>(rowptr, csrc, alpha_all, invden4, feat_all,
                                                         b2, nullptr, Ahi, Alo);

    // ---- layer 3: K=192, Mfeat=96 -> d_out (fp32)
    convert_B_kernel<<<(96 * 192 + 255) / 256, 256, 0, stream>>>(W3, Bhi, Blo, 192, 192, 32, 96);
    convert_Bel_kernel<<<(24 * 192 + 255) / 256, 256, 0, stream>>>(W3, al3, ar3, Bhi, Blo, 192, 192,
                                                                   1, 32, 96);
    gemm_mfma_kernel<<<1 * gy, 256, 0, stream>>>(Ahi, Alo, Bhi, Blo, feat_all, elr, NNODES, 192,
                                                 120, 96, 32, (size_t)NNODES * 32, 1);
    alpha_kernel<1><<<nb, 256, 0, stream>>>(rowptr, csrc, elr, alpha_all, invden4);
    gat_agg_kernel<1, 32, 0><<<aggb32, 256, 0, stream>>>(rowptr, csrc, alpha_all, invden4, feat_all,
                                                         b3, (float*)d_out, nullptr, nullptr);
}